// Round 13
// baseline (315.499 us; speedup 1.0000x reference)
//
#include <hip/hip_runtime.h>
#include <hip/hip_bf16.h>

typedef __attribute__((ext_vector_type(8))) short short8;
typedef __attribute__((ext_vector_type(4))) float f32x4;

__device__ inline unsigned short f2bf(float f) {
  __hip_bfloat16 h = __float2bfloat16(f);
  return *reinterpret_cast<unsigned short*>(&h);
}
__device__ inline float bf2f(unsigned short u) {
  union { unsigned u; float f; } v; v.u = ((unsigned)u) << 16;
  return v.f;
}

#define GLOAD_LDS16(g, l)                                          \
  __builtin_amdgcn_global_load_lds(                                \
      (const __attribute__((address_space(1))) void*)(g),          \
      (__attribute__((address_space(3))) void*)(l), 16, 0, 0)

#define MFMA16(a, b, c) __builtin_amdgcn_mfma_f32_16x16x32_bf16((a), (b), (c), 0, 0, 0)

#define LGKM0()                                              \
  asm volatile("s_waitcnt lgkmcnt(0)" ::: "memory");         \
  __builtin_amdgcn_sched_barrier(0);

// ---------------- fused f32 -> bf16 convert: x, w_attn, w_proj ----------------
__global__ void cvt3(const float* __restrict__ x, const float* __restrict__ wa,
                     const float* __restrict__ wp, unsigned short* __restrict__ Xb,
                     unsigned short* __restrict__ Wa, unsigned short* __restrict__ Wp) {
  const int N_X = 1048576, N_WA = 3145728;          // in short8 groups
  const int TOT = 6291456;
  for (int i = blockIdx.x * 256 + threadIdx.x; i < TOT; i += gridDim.x * 256) {
    const float* src; unsigned short* dst; int off;
    if (i < N_X)            { src = x;  dst = Xb; off = i; }
    else if (i < N_X + N_WA){ src = wa; dst = Wa; off = i - N_X; }
    else                    { src = wp; dst = Wp; off = i - N_X - N_WA; }
    const float4* p = (const float4*)src + (size_t)off * 2;
    float4 a = p[0], b = p[1];
    short8 v;
    v[0] = f2bf(a.x); v[1] = f2bf(a.y); v[2] = f2bf(a.z); v[3] = f2bf(a.w);
    v[4] = f2bf(b.x); v[5] = f2bf(b.y); v[6] = f2bf(b.z); v[7] = f2bf(b.w);
    *((short8*)dst + off) = v;
  }
}

// ======== GEMM1: BM=256 x BN=192, grid 8x32=256, 2 phases/K-tile (R12-verbatim) ====
__global__ __launch_bounds__(512, 2)
void gemm_qkv(const unsigned short* __restrict__ A, const unsigned short* __restrict__ B,
              unsigned short* __restrict__ C, int M, int N, int K) {
  __shared__ __align__(16) unsigned short lds[2][448 * 64];  // A rows 0..255, B rows 256..447
  const int t = threadIdx.x, lane = t & 63, w = t >> 6;
  const int wm = w >> 1, wn = w & 1;              // 4M x 2N
  const int r16 = lane & 15, kg = lane >> 4;
  const int bm = blockIdx.x & 7, bn = blockIdx.x >> 3;  // XCD = bid%8 = bm: A panel L2-resident
  const int NT = K >> 6;
  const int sr = lane >> 3, sch = lane & 7;
  const unsigned short* Ag = A + (size_t)(bm * 256) * K;
  const unsigned short* Bg = B + (size_t)(bn * 192) * K;

  auto stA = [&](int kt, int j, int b) {
    int rl = j * 64 + w * 8 + sr, sc = sch ^ (rl & 7);
    GLOAD_LDS16(Ag + (size_t)rl * K + kt * 64 + sc * 8, &lds[b][(j * 64 + w * 8) * 64]);
  };
  auto stB = [&](int kt, int j, int b) {
    int rl = j * 64 + w * 8 + sr, sc = sch ^ (rl & 7);
    GLOAD_LDS16(Bg + (size_t)rl * K + kt * 64 + sc * 8, &lds[b][(256 + j * 64 + w * 8) * 64]);
  };
  auto lda = [&](int b, int m, int kk) -> short8 {
    int row = wm * 64 + m * 16 + r16, ch = (kk * 4 + kg) ^ (row & 7);
    return *(const short8*)__builtin_assume_aligned(&lds[b][row * 64 + ch * 8], 16);
  };
  auto ldb = [&](int b, int n, int kk) -> short8 {
    int row = wn * 96 + n * 16 + r16, ch = (kk * 4 + kg) ^ (row & 7);
    return *(const short8*)__builtin_assume_aligned(&lds[b][(256 + row) * 64 + ch * 8], 16);
  };

  f32x4 acc[4][6] = {};
  short8 af[4][2], bb[6][2];

#pragma unroll
  for (int j = 0; j < 4; ++j) stA(0, j, 0);
#pragma unroll
  for (int j = 0; j < 3; ++j) stB(0, j, 0);
#pragma unroll
  for (int j = 0; j < 4; ++j) stA(1, j, 1);
  asm volatile("s_waitcnt vmcnt(4)" ::: "memory");
  __builtin_amdgcn_sched_barrier(0);
  __builtin_amdgcn_s_barrier();

  for (int kt = 0; kt < NT; ++kt) {
    const int b = kt & 1;
    const bool pf1 = kt + 1 < NT, pf2 = kt + 2 < NT;

    // ---- P1: spill-stage B0-2(t+1); read a(8)+b01(4); MFMA m0-3 x n0-1 ----
    if (pf1) { stB(kt + 1, 0, b ^ 1); stB(kt + 1, 1, b ^ 1); stB(kt + 1, 2, b ^ 1); }
#pragma unroll
    for (int m = 0; m < 4; ++m) { af[m][0] = lda(b, m, 0); af[m][1] = lda(b, m, 1); }
#pragma unroll
    for (int n = 0; n < 2; ++n) { bb[n][0] = ldb(b, n, 0); bb[n][1] = ldb(b, n, 1); }
    __builtin_amdgcn_s_barrier();
    LGKM0();
    __builtin_amdgcn_s_setprio(1);
#pragma unroll
    for (int m = 0; m < 4; ++m)
#pragma unroll
      for (int n = 0; n < 2; ++n)
#pragma unroll
        for (int kk = 0; kk < 2; ++kk) acc[m][n] = MFMA16(af[m][kk], bb[n][kk], acc[m][n]);
    __builtin_amdgcn_s_setprio(0);
    __builtin_amdgcn_s_barrier();

    // ---- P2: stage A0-3(t+2); read b2-5(8); MFMA m0-3 x n2-5 ----
    if (pf2) { stA(kt + 2, 0, b); stA(kt + 2, 1, b); stA(kt + 2, 2, b); stA(kt + 2, 3, b); }
#pragma unroll
    for (int n = 2; n < 6; ++n) { bb[n][0] = ldb(b, n, 0); bb[n][1] = ldb(b, n, 1); }
    __builtin_amdgcn_s_barrier();
    LGKM0();
    __builtin_amdgcn_s_setprio(1);
#pragma unroll
    for (int m = 0; m < 4; ++m)
#pragma unroll
      for (int n = 2; n < 6; ++n)
#pragma unroll
        for (int kk = 0; kk < 2; ++kk) acc[m][n] = MFMA16(af[m][kk], bb[n][kk], acc[m][n]);
    __builtin_amdgcn_s_setprio(0);
    if (pf1) {
      if (pf2) asm volatile("s_waitcnt vmcnt(4)" ::: "memory");
      else     asm volatile("s_waitcnt vmcnt(0)" ::: "memory");
      __builtin_amdgcn_sched_barrier(0);
      __builtin_amdgcn_s_barrier();
    }
  }

#pragma unroll
  for (int m = 0; m < 4; ++m)
#pragma unroll
    for (int n = 0; n < 6; ++n)
#pragma unroll
      for (int j = 0; j < 4; ++j) {
        int row = bm * 256 + wm * 64 + m * 16 + kg * 4 + j;
        int col = bn * 192 + wn * 96 + n * 16 + r16;
        C[(size_t)row * N + col] = f2bf(acc[m][n][j]);
      }
}

// ======== GEMM2: BM=256 x BN=128, grid 8x32=256, 2 phases/K-tile, f32 out ========
// Clone of gemm_qkv structure: 4M x 2N waves (64x64 tile), spill-staged ledger.
__global__ __launch_bounds__(512, 1)
void gemm_proj(const unsigned short* __restrict__ A, const unsigned short* __restrict__ B,
               float* __restrict__ C, int M, int N, int K) {
  __shared__ __align__(16) unsigned short lds[2][384 * 64];  // A rows 0..255, B rows 256..383
  const int t = threadIdx.x, lane = t & 63, w = t >> 6;
  const int wm = w >> 1, wn = w & 1;              // 4M x 2N
  const int r16 = lane & 15, kg = lane >> 4;
  const int bm = blockIdx.x & 7, bn = blockIdx.x >> 3;  // XCD = bid%8 = bm: A panel L2-resident
  const int NT = K >> 6;
  const int sr = lane >> 3, sch = lane & 7;
  const unsigned short* Ag = A + (size_t)(bm * 256) * K;
  const unsigned short* Bg = B + (size_t)(bn * 128) * K;

  auto stA = [&](int kt, int j, int b) {
    int rl = j * 64 + w * 8 + sr, sc = sch ^ (rl & 7);
    GLOAD_LDS16(Ag + (size_t)rl * K + kt * 64 + sc * 8, &lds[b][(j * 64 + w * 8) * 64]);
  };
  auto stB = [&](int kt, int j, int b) {
    int rl = j * 64 + w * 8 + sr, sc = sch ^ (rl & 7);
    GLOAD_LDS16(Bg + (size_t)rl * K + kt * 64 + sc * 8, &lds[b][(256 + j * 64 + w * 8) * 64]);
  };
  auto lda = [&](int b, int m, int kk) -> short8 {
    int row = wm * 64 + m * 16 + r16, ch = (kk * 4 + kg) ^ (row & 7);
    return *(const short8*)__builtin_assume_aligned(&lds[b][row * 64 + ch * 8], 16);
  };
  auto ldb = [&](int b, int n, int kk) -> short8 {
    int row = wn * 64 + n * 16 + r16, ch = (kk * 4 + kg) ^ (row & 7);
    return *(const short8*)__builtin_assume_aligned(&lds[b][(256 + row) * 64 + ch * 8], 16);
  };

  f32x4 acc[4][4] = {};
  short8 af[4][2], bb[4][2];

  // prologue: tile0 A(4)+B(2); tile1 A(4). B(1) spills into t0's P1.
#pragma unroll
  for (int j = 0; j < 4; ++j) stA(0, j, 0);
#pragma unroll
  for (int j = 0; j < 2; ++j) stB(0, j, 0);
#pragma unroll
  for (int j = 0; j < 4; ++j) stA(1, j, 1);
  asm volatile("s_waitcnt vmcnt(4)" ::: "memory");
  __builtin_amdgcn_sched_barrier(0);
  __builtin_amdgcn_s_barrier();

  for (int kt = 0; kt < NT; ++kt) {
    const int b = kt & 1;
    const bool pf1 = kt + 1 < NT, pf2 = kt + 2 < NT;

    // ---- P1: spill-stage B01(t+1) into b^1 (B reads of b^1 done @t-1 end);
    //          read a(8)+b01(4); MFMA m0-3 x n0-1 ----
    if (pf1) { stB(kt + 1, 0, b ^ 1); stB(kt + 1, 1, b ^ 1); }
#pragma unroll
    for (int m = 0; m < 4; ++m) { af[m][0] = lda(b, m, 0); af[m][1] = lda(b, m, 1); }
#pragma unroll
    for (int n = 0; n < 2; ++n) { bb[n][0] = ldb(b, n, 0); bb[n][1] = ldb(b, n, 1); }
    __builtin_amdgcn_s_barrier();
    LGKM0();
    __builtin_amdgcn_s_setprio(1);
#pragma unroll
    for (int m = 0; m < 4; ++m)
#pragma unroll
      for (int n = 0; n < 2; ++n)
#pragma unroll
        for (int kk = 0; kk < 2; ++kk) acc[m][n] = MFMA16(af[m][kk], bb[n][kk], acc[m][n]);
    __builtin_amdgcn_s_setprio(0);
    __builtin_amdgcn_s_barrier();

    // ---- P2: stage A0-3(t+2) into b (A reads done @P1-end); read b23(4); MFMA m0-3 x n2-3
    if (pf2) { stA(kt + 2, 0, b); stA(kt + 2, 1, b); stA(kt + 2, 2, b); stA(kt + 2, 3, b); }
#pragma unroll
    for (int n = 2; n < 4; ++n) { bb[n][0] = ldb(b, n, 0); bb[n][1] = ldb(b, n, 1); }
    __builtin_amdgcn_s_barrier();
    LGKM0();
    __builtin_amdgcn_s_setprio(1);
#pragma unroll
    for (int m = 0; m < 4; ++m)
#pragma unroll
      for (int n = 2; n < 4; ++n)
#pragma unroll
        for (int kk = 0; kk < 2; ++kk) acc[m][n] = MFMA16(af[m][kk], bb[n][kk], acc[m][n]);
    __builtin_amdgcn_s_setprio(0);
    if (pf1) {  // drain A(t+1)+B(t+1); keep A(t+2)'s 4 in flight
      if (pf2) asm volatile("s_waitcnt vmcnt(4)" ::: "memory");
      else     asm volatile("s_waitcnt vmcnt(0)" ::: "memory");
      __builtin_amdgcn_sched_barrier(0);
      __builtin_amdgcn_s_barrier();
    }
  }

#pragma unroll
  for (int m = 0; m < 4; ++m)
#pragma unroll
    for (int n = 0; n < 4; ++n)
#pragma unroll
      for (int j = 0; j < 4; ++j) {
        int row = bm * 256 + wm * 64 + m * 16 + kg * 4 + j;
        int col = bn * 128 + wn * 64 + n * 16 + r16;
        C[(size_t)row * N + col] = acc[m][n][j];
      }
}

// -------- Merged RoPE (Q scaled by 1/sqrt(hs) * log2(e) for exp2 softmax, K) + V^T ----
__global__ void rope_tv(const unsigned short* __restrict__ qkv,
                        const float* __restrict__ cosb, const float* __restrict__ sinb,
                        unsigned short* __restrict__ Q, unsigned short* __restrict__ K,
                        unsigned short* __restrict__ Vt) {
  __shared__ __align__(16) unsigned short tile[64][136];
  const int bid = blockIdx.x;
  if (bid < 20480) {
    int pair = bid * 4 + (threadIdx.x >> 6);
    int l = threadIdx.x & 63;
    int t = pair / 40, slot = pair - t * 40;
    const unsigned short* src;
    unsigned short* dst;
    float scale;
    if (slot < 32) {
      int g = slot >> 2, j = slot & 3;
      src = qkv + (size_t)t * 6144 + g * 768 + j * 128;
      dst = Q + ((size_t)slot * 2048 + t) * 128;
      scale = 0.08838834764831845f * 1.4426950408889634f;  // 1/sqrt(128) * log2(e)
    } else {
      int g = slot - 32;
      src = qkv + (size_t)t * 6144 + g * 768 + 512;
      dst = K + ((size_t)g * 2048 + t) * 128;
      scale = 1.0f;
    }
    float x1 = bf2f(src[l]), x2 = bf2f(src[64 + l]);
    float c1 = cosb[t * 128 + l], s1 = sinb[t * 128 + l];
    float c2 = cosb[t * 128 + 64 + l], s2 = sinb[t * 128 + 64 + l];
    dst[l]      = f2bf((x1 * c1 - x2 * s1) * scale);
    dst[64 + l] = f2bf((x2 * c2 + x1 * s2) * scale);
  } else {
    int b2 = bid - 20480;              // 0..255
    int g = b2 >> 5, t0 = (b2 & 31) * 64;
    int th = threadIdx.x;
    int r = th >> 2, c0 = (th & 3) * 32;
    const unsigned short* src = qkv + (size_t)(t0 + r) * 6144 + g * 768 + 640 + c0;
#pragma unroll
    for (int i = 0; i < 4; ++i)
      *(short8*)&tile[r][c0 + i * 8] = *(const short8*)(src + i * 8);
    __syncthreads();
    int d = th >> 1, tc = (th & 1) * 32;
    unsigned short* dst = Vt + (size_t)(g * 128 + d) * 2048 + t0 + tc;
#pragma unroll
    for (int j = 0; j < 32; ++j) dst[j] = tile[tc + j][d];
  }
}

// ---------------- Flash attention: swapped QK^T, in-reg exp2 softmax, defer-max, ----
// ---------------- dbuf + 1 barrier/tile, paired q-tiles (33 KV tiles/block) ---------
__global__ __launch_bounds__(256, 2)
void flash_attn(const unsigned short* __restrict__ Q, const unsigned short* __restrict__ K,
                const unsigned short* __restrict__ Vt, unsigned short* __restrict__ Y) {
  __shared__ __align__(16) unsigned short Ksm[2][64 * 128];   // [kv][d], XOR-swizzled
  __shared__ __align__(16) unsigned short Vsm[2][128 * 64];   // [d][kv], XOR-swizzled

  const int h = blockIdx.y, g = h >> 2;
  const int t = threadIdx.x, lane = t & 63, w = t >> 6;
  const int r16 = lane & 15, kg = lane >> 4;
  const bool odd = kg & 1;
  const bool hi = kg >> 1;
  const bool useswap = odd ^ hi;

  const unsigned short* Kg = K + (size_t)g * 2048 * 128;
  const unsigned short* Vg = Vt + (size_t)g * 128 * 2048;

  const int krl = lane >> 4, kc = lane & 15;
  const int vrl = lane >> 3, vc = lane & 7;

  auto stage = [&](int kvs, int b) {
#pragma unroll
    for (int i = 0; i < 4; ++i) {
      int row = w * 16 + i * 4 + krl;
      int sc = kc ^ (row & 7);
      GLOAD_LDS16(Kg + (size_t)(kvs + row) * 128 + sc * 8,
                  &Ksm[b][(w * 16 + i * 4) * 128]);
    }
#pragma unroll
    for (int i = 0; i < 4; ++i) {
      int d = w * 32 + i * 8 + vrl;
      int sc = vc ^ (d & 7);
      GLOAD_LDS16(Vg + (size_t)d * 2048 + kvs + sc * 8,
                  &Vsm[b][(w * 32 + i * 8) * 64]);
    }
  };

  auto process = [&](int q0) {
    short8 qf[4];
    const unsigned short* qrow = Q + ((size_t)h * 2048 + q0 + w * 16 + r16) * 128;
#pragma unroll
    for (int kk = 0; kk < 4; ++kk) qf[kk] = *(const short8*)(qrow + kk * 32 + kg * 8);

    f32x4 o[8] = {};
    float mrow = -1e30f, lrow = 0.f;
    const int qg = q0 + w * 16 + r16;
    const int nt = q0 / 64 + 1;

    __syncthreads();
    stage(0, 0);

    for (int kt = 0; kt < nt; ++kt) {
      const int b = kt & 1;
      const int kv0 = kt * 64;
      __syncthreads();
      if (kt + 1 < nt) stage((kt + 1) * 64, b ^ 1);

      f32x4 s[4] = {};
      __builtin_amdgcn_s_setprio(1);
#pragma unroll
      for (int n = 0; n < 4; ++n) {
        int kr = n * 16 + r16;
#pragma unroll
        for (int kk = 0; kk < 4; ++kk) {
          short8 kf = *(const short8*)__builtin_assume_aligned(
              &Ksm[b][kr * 128 + ((kk * 32 + kg * 8) ^ ((kr & 7) << 3))], 16);
          s[n] = __builtin_amdgcn_mfma_f32_16x16x32_bf16(kf, qf[kk], s[n], 0, 0, 0);
        }
      }
      __builtin_amdgcn_s_setprio(0);

      if (kv0 + 63 > q0 + w * 16) {
#pragma unroll
        for (int n = 0; n < 4; ++n)
#pragma unroll
          for (int j = 0; j < 4; ++j)
            if (kv0 + n * 16 + kg * 4 + j > qg) s[n][j] = -1e30f;
      }

      float rmax = -1e30f;
#pragma unroll
      for (int n = 0; n < 4; ++n)
#pragma unroll
        for (int j = 0; j < 4; ++j) rmax = fmaxf(rmax, s[n][j]);
      rmax = fmaxf(rmax, __shfl_xor(rmax, 16));
      rmax = fmaxf(rmax, __shfl_xor(rmax, 32));

      // defer-max (T13): rescale only when the running max grew by > 8 (log2 domain).
      // Exact math: P = 2^(s - mrow) <= 2^8; normalization by lrow corrects it.
      if (__builtin_amdgcn_ballot_w64(rmax > mrow + 8.0f)) {
        float mnew = fmaxf(mrow, rmax);
        float fac = exp2f(mrow - mnew);
        mrow = mnew;
        lrow *= fac;
        float fj[4];
#pragma unroll
        for (int j = 0; j < 4; ++j) fj[j] = __shfl(fac, kg * 4 + j);
#pragma unroll
        for (int f = 0; f < 8; ++f)
#pragma unroll
          for (int j = 0; j < 4; ++j) o[f][j] *= fj[j];
      }

      float p[4][4];
      float rs = 0.f;
#pragma unroll
      for (int n = 0; n < 4; ++n)
#pragma unroll
        for (int j = 0; j < 4; ++j) {
          p[n][j] = exp2f(s[n][j] - mrow);
          rs += p[n][j];
        }
      rs += __shfl_xor(rs, 16);
      rs += __shfl_xor(rs, 32);
      lrow += rs;

      unsigned bpk[4][2], xpk[4][2];
#pragma unroll
      for (int n = 0; n < 4; ++n)
#pragma unroll
        for (int i = 0; i < 2; ++i)
          bpk[n][i] = (unsigned)f2bf(p[n][2 * i]) | ((unsigned)f2bf(p[n][2 * i + 1]) << 16);
#pragma unroll
      for (int n = 0; n < 4; ++n)
#pragma unroll
        for (int i = 0; i < 2; ++i) xpk[n][i] = __shfl_xor(bpk[n][i], 16);

      unsigned pl[4][2], ph[4][2];
#pragma unroll
      for (int n = 0; n < 4; ++n)
#pragma unroll
        for (int i = 0; i < 2; ++i) {
          pl[n][i] = odd ? xpk[n][i] : bpk[n][i];
          ph[n][i] = odd ? bpk[n][i] : xpk[n][i];
        }

      short8 pa[2];
#pragma unroll
      for (int kk = 0; kk < 2; ++kk) {
        unsigned kp0 = hi ? pl[2 * kk + 1][0] : pl[2 * kk][0];
        unsigned kp1 = hi ? pl[2 * kk + 1][1] : pl[2 * kk][1];
        unsigned kp2 = hi ? ph[2 * kk + 1][0] : ph[2 * kk][0];
        unsigned kp3 = hi ? ph[2 * kk + 1][1] : ph[2 * kk][1];
        unsigned sd0 = hi ? pl[2 * kk][0] : pl[2 * kk + 1][0];
        unsigned sd1 = hi ? pl[2 * kk][1] : pl[2 * kk + 1][1];
        unsigned sd2 = hi ? ph[2 * kk][0] : ph[2 * kk + 1][0];
        unsigned sd3 = hi ? ph[2 * kk][1] : ph[2 * kk + 1][1];
        unsigned g0 = __shfl_xor(sd0, 32), g1 = __shfl_xor(sd1, 32);
        unsigned g2 = __shfl_xor(sd2, 32), g3 = __shfl_xor(sd3, 32);
        union { unsigned u[4]; short8 v; } pu;
        pu.u[0] = useswap ? g0 : kp0;
        pu.u[1] = useswap ? g1 : kp1;
        pu.u[2] = useswap ? g2 : kp2;
        pu.u[3] = useswap ? g3 : kp3;
        pa[kk] = pu.v;
      }

      __builtin_amdgcn_s_setprio(1);
#pragma unroll
      for (int kk = 0; kk < 2; ++kk) {
#pragma unroll
        for (int f = 0; f < 8; ++f) {
          int d = f * 16 + r16;
          short8 vf = *(const short8*)__builtin_assume_aligned(
              &Vsm[b][d * 64 + ((kk * 32 + kg * 8) ^ ((d & 7) << 3))], 16);
          o[f] = __builtin_amdgcn_mfma_f32_16x16x32_bf16(pa[kk], vf, o[f], 0, 0, 0);
        }
      }
      __builtin_amdgcn_s_setprio(0);
    }

    float inv = 1.f / lrow;
    float invj[4];
#pragma unroll
    for (int j = 0; j < 4; ++j) invj[j] = __shfl(inv, kg * 4 + j);
#pragma unroll
    for (int j = 0; j < 4; ++j) {
      int row = q0 + w * 16 + kg * 4 + j;
      unsigned short* yr = Y + (size_t)row * 4096 + h * 128;
#pragma unroll
      for (int f = 0; f < 8; ++f) yr[f * 16 + r16] = f2bf(o[f][j] * invj[j]);
    }
  };

  const int pr = blockIdx.x;      // 0..15
  process(pr * 64);               // light tile
  process((31 - pr) * 64);        // heavy tile: total 33 KV-tiles per block
}

extern "C" void kernel_launch(void* const* d_in, const int* in_sizes, int n_in,
                              void* d_out, int out_size, void* d_ws, size_t ws_size,
                              hipStream_t stream) {
  const float* x      = (const float*)d_in[0];
  const float* cosb   = (const float*)d_in[1];
  const float* sinb   = (const float*)d_in[2];
  const float* w_attn = (const float*)d_in[3];
  const float* w_proj = (const float*)d_in[4];
  float* out = (float*)d_out;

  char* ws = (char*)d_ws;
  const size_t MB = 1024 * 1024;
  unsigned short* Xb  = (unsigned short*)(ws);
  unsigned short* Wa  = (unsigned short*)(ws + 16 * MB);
  unsigned short* Wp  = (unsigned short*)(ws + 112 * MB);
  unsigned short* Qb  = (unsigned short*)(ws + 32 * MB);  // after gemm1
  unsigned short* Kb  = (unsigned short*)(ws + 48 * MB);  // after gemm1
  unsigned short* Vt  = (unsigned short*)(ws + 52 * MB);  // after gemm1
  unsigned short* qkv = (unsigned short*)(ws + 64 * MB);
  unsigned short* Yb  = (unsigned short*)(ws + 88 * MB);

  cvt3<<<2048, 256, 0, stream>>>(x, w_attn, w_proj, Xb, Wa, Wp);
  gemm_qkv<<<256, 512, 0, stream>>>(Xb, Wa, qkv, 2048, 6144, 4096);
  rope_tv<<<20736, 256, 0, stream>>>(qkv, cosb, sinb, Qb, Kb, Vt);
  flash_attn<<<dim3(16, 32), 256, 0, stream>>>(Qb, Kb, Vt, Yb);
  gemm_proj<<<256, 512, 0, stream>>>(Yb, Wp, out, 2048, 4096, 4096);
}

// Round 14
// 314.613 us; speedup vs baseline: 1.0028x; 1.0028x over previous
//
#include <hip/hip_runtime.h>
#include <hip/hip_bf16.h>

typedef __attribute__((ext_vector_type(8))) short short8;
typedef __attribute__((ext_vector_type(4))) float f32x4;

__device__ inline unsigned short f2bf(float f) {
  __hip_bfloat16 h = __float2bfloat16(f);
  return *reinterpret_cast<unsigned short*>(&h);
}
__device__ inline float bf2f(unsigned short u) {
  union { unsigned u; float f; } v; v.u = ((unsigned)u) << 16;
  return v.f;
}

#define GLOAD_LDS16(g, l)                                          \
  __builtin_amdgcn_global_load_lds(                                \
      (const __attribute__((address_space(1))) void*)(g),          \
      (__attribute__((address_space(3))) void*)(l), 16, 0, 0)

#define MFMA16(a, b, c) __builtin_amdgcn_mfma_f32_16x16x32_bf16((a), (b), (c), 0, 0, 0)

// vmcnt(0) + fence + barrier: the asm memory clobber stops the compiler from
// hoisting next-tile ds_reads above the barrier (raw s_barrier is not an IR fence).
#define TILE_BARRIER()                                       \
  asm volatile("s_waitcnt vmcnt(0)" ::: "memory");           \
  __builtin_amdgcn_sched_barrier(0);                         \
  __builtin_amdgcn_s_barrier();

// ---------------- fused f32 -> bf16 convert: x, w_attn, w_proj ----------------
__global__ void cvt3(const float* __restrict__ x, const float* __restrict__ wa,
                     const float* __restrict__ wp, unsigned short* __restrict__ Xb,
                     unsigned short* __restrict__ Wa, unsigned short* __restrict__ Wp) {
  const int N_X = 1048576, N_WA = 3145728;          // in short8 groups
  const int TOT = 6291456;
  for (int i = blockIdx.x * 256 + threadIdx.x; i < TOT; i += gridDim.x * 256) {
    const float* src; unsigned short* dst; int off;
    if (i < N_X)            { src = x;  dst = Xb; off = i; }
    else if (i < N_X + N_WA){ src = wa; dst = Wa; off = i - N_X; }
    else                    { src = wp; dst = Wp; off = i - N_X - N_WA; }
    const float4* p = (const float4*)src + (size_t)off * 2;
    float4 a = p[0], b = p[1];
    short8 v;
    v[0] = f2bf(a.x); v[1] = f2bf(a.y); v[2] = f2bf(a.z); v[3] = f2bf(a.w);
    v[4] = f2bf(b.x); v[5] = f2bf(b.y); v[6] = f2bf(b.z); v[7] = f2bf(b.w);
    *((short8*)dst + off) = v;
  }
}

// ======== GEMM1: BM=256 x BN=192, grid 8x32=256, ONE barrier/K-tile ========
// All 20 ds_reads issued at tile top (compiler inserts counted lgkm waits before
// each MFMA use -> reads overlap MFMA); 7 gload_lds stages for t+1 land under the
// 48-MFMA cluster; vmcnt(0)+barrier once per tile.
__global__ __launch_bounds__(512, 2)
void gemm_qkv(const unsigned short* __restrict__ A, const unsigned short* __restrict__ B,
              unsigned short* __restrict__ C, int M, int N, int K) {
  __shared__ __align__(16) unsigned short lds[2][448 * 64];  // A rows 0..255, B rows 256..447
  const int t = threadIdx.x, lane = t & 63, w = t >> 6;
  const int wm = w >> 1, wn = w & 1;              // 4M x 2N
  const int r16 = lane & 15, kg = lane >> 4;
  const int bm = blockIdx.x & 7, bn = blockIdx.x >> 3;  // XCD = bid%8 = bm: A panel L2-resident
  const int NT = K >> 6;
  const int sr = lane >> 3, sch = lane & 7;
  const unsigned short* Ag = A + (size_t)(bm * 256) * K;
  const unsigned short* Bg = B + (size_t)(bn * 192) * K;

  auto stA = [&](int kt, int j, int b) {
    int rl = j * 64 + w * 8 + sr, sc = sch ^ (rl & 7);
    GLOAD_LDS16(Ag + (size_t)rl * K + kt * 64 + sc * 8, &lds[b][(j * 64 + w * 8) * 64]);
  };
  auto stB = [&](int kt, int j, int b) {
    int rl = j * 64 + w * 8 + sr, sc = sch ^ (rl & 7);
    GLOAD_LDS16(Bg + (size_t)rl * K + kt * 64 + sc * 8, &lds[b][(256 + j * 64 + w * 8) * 64]);
  };
  auto lda = [&](int b, int m, int kk) -> short8 {
    int row = wm * 64 + m * 16 + r16, ch = (kk * 4 + kg) ^ (row & 7);
    return *(const short8*)__builtin_assume_aligned(&lds[b][row * 64 + ch * 8], 16);
  };
  auto ldb = [&](int b, int n, int kk) -> short8 {
    int row = wn * 96 + n * 16 + r16, ch = (kk * 4 + kg) ^ (row & 7);
    return *(const short8*)__builtin_assume_aligned(&lds[b][(256 + row) * 64 + ch * 8], 16);
  };

  f32x4 acc[4][6] = {};
  short8 af[4][2], bb[6][2];

  // prologue: stage tile0 -> buf0, drain, barrier
#pragma unroll
  for (int j = 0; j < 4; ++j) stA(0, j, 0);
#pragma unroll
  for (int j = 0; j < 3; ++j) stB(0, j, 0);
  TILE_BARRIER();

  for (int kt = 0; kt < NT; ++kt) {
    const int b = kt & 1;
    const bool pf1 = kt + 1 < NT;

    // all 20 ds_reads from buf b (consumed below; compiler emits counted lgkm waits)
#pragma unroll
    for (int m = 0; m < 4; ++m) { af[m][0] = lda(b, m, 0); af[m][1] = lda(b, m, 1); }
#pragma unroll
    for (int n = 0; n < 6; ++n) { bb[n][0] = ldb(b, n, 0); bb[n][1] = ldb(b, n, 1); }

    // stage tile t+1 -> b^1 (its reads were consumed at t-1; barrier passed => safe)
    if (pf1) {
      stB(kt + 1, 0, b ^ 1); stB(kt + 1, 1, b ^ 1); stB(kt + 1, 2, b ^ 1);
      stA(kt + 1, 0, b ^ 1); stA(kt + 1, 1, b ^ 1); stA(kt + 1, 2, b ^ 1); stA(kt + 1, 3, b ^ 1);
    }

    __builtin_amdgcn_s_setprio(1);
#pragma unroll
    for (int m = 0; m < 4; ++m)
#pragma unroll
      for (int n = 0; n < 6; ++n)
#pragma unroll
        for (int kk = 0; kk < 2; ++kk) acc[m][n] = MFMA16(af[m][kk], bb[n][kk], acc[m][n]);
    __builtin_amdgcn_s_setprio(0);

    if (pf1) { TILE_BARRIER(); }
  }

#pragma unroll
  for (int m = 0; m < 4; ++m)
#pragma unroll
    for (int n = 0; n < 6; ++n)
#pragma unroll
      for (int j = 0; j < 4; ++j) {
        int row = bm * 256 + wm * 64 + m * 16 + kg * 4 + j;
        int col = bn * 192 + wn * 96 + n * 16 + r16;
        C[(size_t)row * N + col] = f2bf(acc[m][n][j]);
      }
}

// ======== GEMM2: BM=256 x BN=128, grid 8x32=256, ONE barrier/K-tile, f32 out ========
__global__ __launch_bounds__(512, 2)
void gemm_proj(const unsigned short* __restrict__ A, const unsigned short* __restrict__ B,
               float* __restrict__ C, int M, int N, int K) {
  __shared__ __align__(16) unsigned short lds[2][384 * 64];  // A rows 0..255, B rows 256..383
  const int t = threadIdx.x, lane = t & 63, w = t >> 6;
  const int wm = w >> 1, wn = w & 1;              // 4M x 2N
  const int r16 = lane & 15, kg = lane >> 4;
  const int bm = blockIdx.x & 7, bn = blockIdx.x >> 3;  // XCD = bid%8 = bm
  const int NT = K >> 6;
  const int sr = lane >> 3, sch = lane & 7;
  const unsigned short* Ag = A + (size_t)(bm * 256) * K;
  const unsigned short* Bg = B + (size_t)(bn * 128) * K;

  auto stA = [&](int kt, int j, int b) {
    int rl = j * 64 + w * 8 + sr, sc = sch ^ (rl & 7);
    GLOAD_LDS16(Ag + (size_t)rl * K + kt * 64 + sc * 8, &lds[b][(j * 64 + w * 8) * 64]);
  };
  auto stB = [&](int kt, int j, int b) {
    int rl = j * 64 + w * 8 + sr, sc = sch ^ (rl & 7);
    GLOAD_LDS16(Bg + (size_t)rl * K + kt * 64 + sc * 8, &lds[b][(256 + j * 64 + w * 8) * 64]);
  };
  auto lda = [&](int b, int m, int kk) -> short8 {
    int row = wm * 64 + m * 16 + r16, ch = (kk * 4 + kg) ^ (row & 7);
    return *(const short8*)__builtin_assume_aligned(&lds[b][row * 64 + ch * 8], 16);
  };
  auto ldb = [&](int b, int n, int kk) -> short8 {
    int row = wn * 64 + n * 16 + r16, ch = (kk * 4 + kg) ^ (row & 7);
    return *(const short8*)__builtin_assume_aligned(&lds[b][(256 + row) * 64 + ch * 8], 16);
  };

  f32x4 acc[4][4] = {};
  short8 af[4][2], bb[4][2];

  // prologue: stage tile0 -> buf0
#pragma unroll
  for (int j = 0; j < 4; ++j) stA(0, j, 0);
#pragma unroll
  for (int j = 0; j < 2; ++j) stB(0, j, 0);
  TILE_BARRIER();

  for (int kt = 0; kt < NT; ++kt) {
    const int b = kt & 1;
    const bool pf1 = kt + 1 < NT;

    // all 16 ds_reads from buf b
#pragma unroll
    for (int m = 0; m < 4; ++m) { af[m][0] = lda(b, m, 0); af[m][1] = lda(b, m, 1); }
#pragma unroll
    for (int n = 0; n < 4; ++n) { bb[n][0] = ldb(b, n, 0); bb[n][1] = ldb(b, n, 1); }

    // stage tile t+1 -> b^1 (6 issues)
    if (pf1) {
      stB(kt + 1, 0, b ^ 1); stB(kt + 1, 1, b ^ 1);
      stA(kt + 1, 0, b ^ 1); stA(kt + 1, 1, b ^ 1); stA(kt + 1, 2, b ^ 1); stA(kt + 1, 3, b ^ 1);
    }

    __builtin_amdgcn_s_setprio(1);
#pragma unroll
    for (int m = 0; m < 4; ++m)
#pragma unroll
      for (int n = 0; n < 4; ++n)
#pragma unroll
        for (int kk = 0; kk < 2; ++kk) acc[m][n] = MFMA16(af[m][kk], bb[n][kk], acc[m][n]);
    __builtin_amdgcn_s_setprio(0);

    if (pf1) { TILE_BARRIER(); }
  }

#pragma unroll
  for (int m = 0; m < 4; ++m)
#pragma unroll
    for (int n = 0; n < 4; ++n)
#pragma unroll
      for (int j = 0; j < 4; ++j) {
        int row = bm * 256 + wm * 64 + m * 16 + kg * 4 + j;
        int col = bn * 128 + wn * 64 + n * 16 + r16;
        C[(size_t)row * N + col] = acc[m][n][j];
      }
}

// -------- Merged RoPE (Q scaled by 1/sqrt(hs) * log2(e) for exp2 softmax, K) + V^T ----
__global__ void rope_tv(const unsigned short* __restrict__ qkv,
                        const float* __restrict__ cosb, const float* __restrict__ sinb,
                        unsigned short* __restrict__ Q, unsigned short* __restrict__ K,
                        unsigned short* __restrict__ Vt) {
  __shared__ __align__(16) unsigned short tile[64][136];
  const int bid = blockIdx.x;
  if (bid < 20480) {
    int pair = bid * 4 + (threadIdx.x >> 6);
    int l = threadIdx.x & 63;
    int t = pair / 40, slot = pair - t * 40;
    const unsigned short* src;
    unsigned short* dst;
    float scale;
    if (slot < 32) {
      int g = slot >> 2, j = slot & 3;
      src = qkv + (size_t)t * 6144 + g * 768 + j * 128;
      dst = Q + ((size_t)slot * 2048 + t) * 128;
      scale = 0.08838834764831845f * 1.4426950408889634f;  // 1/sqrt(128) * log2(e)
    } else {
      int g = slot - 32;
      src = qkv + (size_t)t * 6144 + g * 768 + 512;
      dst = K + ((size_t)g * 2048 + t) * 128;
      scale = 1.0f;
    }
    float x1 = bf2f(src[l]), x2 = bf2f(src[64 + l]);
    float c1 = cosb[t * 128 + l], s1 = sinb[t * 128 + l];
    float c2 = cosb[t * 128 + 64 + l], s2 = sinb[t * 128 + 64 + l];
    dst[l]      = f2bf((x1 * c1 - x2 * s1) * scale);
    dst[64 + l] = f2bf((x2 * c2 + x1 * s2) * scale);
  } else {
    int b2 = bid - 20480;              // 0..255
    int g = b2 >> 5, t0 = (b2 & 31) * 64;
    int th = threadIdx.x;
    int r = th >> 2, c0 = (th & 3) * 32;
    const unsigned short* src = qkv + (size_t)(t0 + r) * 6144 + g * 768 + 640 + c0;
#pragma unroll
    for (int i = 0; i < 4; ++i)
      *(short8*)&tile[r][c0 + i * 8] = *(const short8*)(src + i * 8);
    __syncthreads();
    int d = th >> 1, tc = (th & 1) * 32;
    unsigned short* dst = Vt + (size_t)(g * 128 + d) * 2048 + t0 + tc;
#pragma unroll
    for (int j = 0; j < 32; ++j) dst[j] = tile[tc + j][d];
  }
}

// ---------------- Flash attention (R13-verbatim): swapped QK^T, in-reg exp2 softmax, --
// ---------------- defer-max, dbuf + 1 barrier/tile, paired q-tiles --------------------
__global__ __launch_bounds__(256, 2)
void flash_attn(const unsigned short* __restrict__ Q, const unsigned short* __restrict__ K,
                const unsigned short* __restrict__ Vt, unsigned short* __restrict__ Y) {
  __shared__ __align__(16) unsigned short Ksm[2][64 * 128];   // [kv][d], XOR-swizzled
  __shared__ __align__(16) unsigned short Vsm[2][128 * 64];   // [d][kv], XOR-swizzled

  const int h = blockIdx.y, g = h >> 2;
  const int t = threadIdx.x, lane = t & 63, w = t >> 6;
  const int r16 = lane & 15, kg = lane >> 4;
  const bool odd = kg & 1;
  const bool hi = kg >> 1;
  const bool useswap = odd ^ hi;

  const unsigned short* Kg = K + (size_t)g * 2048 * 128;
  const unsigned short* Vg = Vt + (size_t)g * 128 * 2048;

  const int krl = lane >> 4, kc = lane & 15;
  const int vrl = lane >> 3, vc = lane & 7;

  auto stage = [&](int kvs, int b) {
#pragma unroll
    for (int i = 0; i < 4; ++i) {
      int row = w * 16 + i * 4 + krl;
      int sc = kc ^ (row & 7);
      GLOAD_LDS16(Kg + (size_t)(kvs + row) * 128 + sc * 8,
                  &Ksm[b][(w * 16 + i * 4) * 128]);
    }
#pragma unroll
    for (int i = 0; i < 4; ++i) {
      int d = w * 32 + i * 8 + vrl;
      int sc = vc ^ (d & 7);
      GLOAD_LDS16(Vg + (size_t)d * 2048 + kvs + sc * 8,
                  &Vsm[b][(w * 32 + i * 8) * 64]);
    }
  };

  auto process = [&](int q0) {
    short8 qf[4];
    const unsigned short* qrow = Q + ((size_t)h * 2048 + q0 + w * 16 + r16) * 128;
#pragma unroll
    for (int kk = 0; kk < 4; ++kk) qf[kk] = *(const short8*)(qrow + kk * 32 + kg * 8);

    f32x4 o[8] = {};
    float mrow = -1e30f, lrow = 0.f;
    const int qg = q0 + w * 16 + r16;
    const int nt = q0 / 64 + 1;

    __syncthreads();
    stage(0, 0);

    for (int kt = 0; kt < nt; ++kt) {
      const int b = kt & 1;
      const int kv0 = kt * 64;
      __syncthreads();
      if (kt + 1 < nt) stage((kt + 1) * 64, b ^ 1);

      f32x4 s[4] = {};
      __builtin_amdgcn_s_setprio(1);
#pragma unroll
      for (int n = 0; n < 4; ++n) {
        int kr = n * 16 + r16;
#pragma unroll
        for (int kk = 0; kk < 4; ++kk) {
          short8 kf = *(const short8*)__builtin_assume_aligned(
              &Ksm[b][kr * 128 + ((kk * 32 + kg * 8) ^ ((kr & 7) << 3))], 16);
          s[n] = __builtin_amdgcn_mfma_f32_16x16x32_bf16(kf, qf[kk], s[n], 0, 0, 0);
        }
      }
      __builtin_amdgcn_s_setprio(0);

      if (kv0 + 63 > q0 + w * 16) {
#pragma unroll
        for (int n = 0; n < 4; ++n)
#pragma unroll
          for (int j = 0; j < 4; ++j)
            if (kv0 + n * 16 + kg * 4 + j > qg) s[n][j] = -1e30f;
      }

      float rmax = -1e30f;
#pragma unroll
      for (int n = 0; n < 4; ++n)
#pragma unroll
        for (int j = 0; j < 4; ++j) rmax = fmaxf(rmax, s[n][j]);
      rmax = fmaxf(rmax, __shfl_xor(rmax, 16));
      rmax = fmaxf(rmax, __shfl_xor(rmax, 32));

      if (__builtin_amdgcn_ballot_w64(rmax > mrow + 8.0f)) {
        float mnew = fmaxf(mrow, rmax);
        float fac = exp2f(mrow - mnew);
        mrow = mnew;
        lrow *= fac;
        float fj[4];
#pragma unroll
        for (int j = 0; j < 4; ++j) fj[j] = __shfl(fac, kg * 4 + j);
#pragma unroll
        for (int f = 0; f < 8; ++f)
#pragma unroll
          for (int j = 0; j < 4; ++j) o[f][j] *= fj[j];
      }

      float p[4][4];
      float rs = 0.f;
#pragma unroll
      for (int n = 0; n < 4; ++n)
#pragma unroll
        for (int j = 0; j < 4; ++j) {
          p[n][j] = exp2f(s[n][j] - mrow);
          rs += p[n][j];
        }
      rs += __shfl_xor(rs, 16);
      rs += __shfl_xor(rs, 32);
      lrow += rs;

      unsigned bpk[4][2], xpk[4][2];
#pragma unroll
      for (int n = 0; n < 4; ++n)
#pragma unroll
        for (int i = 0; i < 2; ++i)
          bpk[n][i] = (unsigned)f2bf(p[n][2 * i]) | ((unsigned)f2bf(p[n][2 * i + 1]) << 16);
#pragma unroll
      for (int n = 0; n < 4; ++n)
#pragma unroll
        for (int i = 0; i < 2; ++i) xpk[n][i] = __shfl_xor(bpk[n][i], 16);

      unsigned pl[4][2], ph[4][2];
#pragma unroll
      for (int n = 0; n < 4; ++n)
#pragma unroll
        for (int i = 0; i < 2; ++i) {
          pl[n][i] = odd ? xpk[n][i] : bpk[n][i];
          ph[n][i] = odd ? bpk[n][i] : xpk[n][i];
        }

      short8 pa[2];
#pragma unroll
      for (int kk = 0; kk < 2; ++kk) {
        unsigned kp0 = hi ? pl[2 * kk + 1][0] : pl[2 * kk][0];
        unsigned kp1 = hi ? pl[2 * kk + 1][1] : pl[2 * kk][1];
        unsigned kp2 = hi ? ph[2 * kk + 1][0] : ph[2 * kk][0];
        unsigned kp3 = hi ? ph[2 * kk + 1][1] : ph[2 * kk][1];
        unsigned sd0 = hi ? pl[2 * kk][0] : pl[2 * kk + 1][0];
        unsigned sd1 = hi ? pl[2 * kk][1] : pl[2 * kk + 1][1];
        unsigned sd2 = hi ? ph[2 * kk][0] : ph[2 * kk + 1][0];
        unsigned sd3 = hi ? ph[2 * kk][1] : ph[2 * kk + 1][1];
        unsigned g0 = __shfl_xor(sd0, 32), g1 = __shfl_xor(sd1, 32);
        unsigned g2 = __shfl_xor(sd2, 32), g3 = __shfl_xor(sd3, 32);
        union { unsigned u[4]; short8 v; } pu;
        pu.u[0] = useswap ? g0 : kp0;
        pu.u[1] = useswap ? g1 : kp1;
        pu.u[2] = useswap ? g2 : kp2;
        pu.u[3] = useswap ? g3 : kp3;
        pa[kk] = pu.v;
      }

      __builtin_amdgcn_s_setprio(1);
#pragma unroll
      for (int kk = 0; kk < 2; ++kk) {
#pragma unroll
        for (int f = 0; f < 8; ++f) {
          int d = f * 16 + r16;
          short8 vf = *(const short8*)__builtin_assume_aligned(
              &Vsm[b][d * 64 + ((kk * 32 + kg * 8) ^ ((d & 7) << 3))], 16);
          o[f] = __builtin_amdgcn_mfma_f32_16x16x32_bf16(pa[kk], vf, o[f], 0, 0, 0);
        }
      }
      __builtin_amdgcn_s_setprio(0);
    }

    float inv = 1.f / lrow;
    float invj[4];
#pragma unroll
    for (int j = 0; j < 4; ++j) invj[j] = __shfl(inv, kg * 4 + j);
#pragma unroll
    for (int j = 0; j < 4; ++j) {
      int row = q0 + w * 16 + kg * 4 + j;
      unsigned short* yr = Y + (size_t)row * 4096 + h * 128;
#pragma unroll
      for (int f = 0; f < 8; ++f) yr[f * 16 + r16] = f2bf(o[f][j] * invj[j]);
    }
  };

  const int pr = blockIdx.x;      // 0..15
  process(pr * 64);               // light tile
  process((31 - pr) * 64);        // heavy tile: total 33 KV-tiles per block
}

extern "C" void kernel_launch(void* const* d_in, const int* in_sizes, int n_in,
                              void* d_out, int out_size, void* d_ws, size_t ws_size,
                              hipStream_t stream) {
  const float* x      = (const float*)d_in[0];
  const float* cosb   = (const float*)d_in[1];
  const float* sinb   = (const float*)d_in[2];
  const float* w_attn = (const float*)d_in[3];
  const float* w_proj = (const float*)d_in[4];
  float* out = (float*)d_out;

  char* ws = (char*)d_ws;
  const size_t MB = 1024 * 1024;
  unsigned short* Xb  = (unsigned short*)(ws);
  unsigned short* Wa  = (unsigned short*)(ws + 16 * MB);
  unsigned short* Wp  = (unsigned short*)(ws + 112 * MB);
  unsigned short* Qb  = (unsigned short*)(ws + 32 * MB);  // after gemm1
  unsigned short* Kb  = (unsigned short*)(ws + 48 * MB);  // after gemm1
  unsigned short* Vt  = (unsigned short*)(ws + 52 * MB);  // after gemm1
  unsigned short* qkv = (unsigned short*)(ws + 64 * MB);
  unsigned short* Yb  = (unsigned short*)(ws + 88 * MB);

  cvt3<<<2048, 256, 0, stream>>>(x, w_attn, w_proj, Xb, Wa, Wp);
  gemm_qkv<<<256, 512, 0, stream>>>(Xb, Wa, qkv, 2048, 6144, 4096);
  rope_tv<<<20736, 256, 0, stream>>>(qkv, cosb, sinb, Qb, Kb, Vt);
  flash_attn<<<dim3(16, 32), 256, 0, stream>>>(Qb, Kb, Vt, Yb);
  gemm_proj<<<256, 512, 0, stream>>>(Yb, Wp, out, 2048, 4096, 4096);
}

// Round 15
// 313.428 us; speedup vs baseline: 1.0066x; 1.0038x over previous
//
#include <hip/hip_runtime.h>
#include <hip/hip_bf16.h>

typedef __attribute__((ext_vector_type(8))) short short8;
typedef __attribute__((ext_vector_type(4))) float f32x4;

__device__ inline unsigned short f2bf(float f) {
  __hip_bfloat16 h = __float2bfloat16(f);
  return *reinterpret_cast<unsigned short*>(&h);
}
__device__ inline float bf2f(unsigned short u) {
  union { unsigned u; float f; } v; v.u = ((unsigned)u) << 16;
  return v.f;
}

#define GLOAD_LDS16(g, l)                                          \
  __builtin_amdgcn_global_load_lds(                                \
      (const __attribute__((address_space(1))) void*)(g),          \
      (__attribute__((address_space(3))) void*)(l), 16, 0, 0)

#define MFMA16(a, b, c) __builtin_amdgcn_mfma_f32_16x16x32_bf16((a), (b), (c), 0, 0, 0)

#define LGKM0()                                              \
  asm volatile("s_waitcnt lgkmcnt(0)" ::: "memory");         \
  __builtin_amdgcn_sched_barrier(0);

// ---------------- fused f32 -> bf16 convert: x, w_attn, w_proj ----------------
__global__ void cvt3(const float* __restrict__ x, const float* __restrict__ wa,
                     const float* __restrict__ wp, unsigned short* __restrict__ Xb,
                     unsigned short* __restrict__ Wa, unsigned short* __restrict__ Wp) {
  const int N_X = 1048576, N_WA = 3145728;          // in short8 groups
  const int TOT = 6291456;
  for (int i = blockIdx.x * 256 + threadIdx.x; i < TOT; i += gridDim.x * 256) {
    const float* src; unsigned short* dst; int off;
    if (i < N_X)            { src = x;  dst = Xb; off = i; }
    else if (i < N_X + N_WA){ src = wa; dst = Wa; off = i - N_X; }
    else                    { src = wp; dst = Wp; off = i - N_X - N_WA; }
    const float4* p = (const float4*)src + (size_t)off * 2;
    float4 a = p[0], b = p[1];
    short8 v;
    v[0] = f2bf(a.x); v[1] = f2bf(a.y); v[2] = f2bf(a.z); v[3] = f2bf(a.w);
    v[4] = f2bf(b.x); v[5] = f2bf(b.y); v[6] = f2bf(b.z); v[7] = f2bf(b.w);
    *((short8*)dst + off) = v;
  }
}

// ======== GEMM1: BM=256 x BN=192, grid 8x32=256, 2 phases/K-tile ========
// Waves 4M x 2N (wave tile 64x96): 20 LDS reads / 48 MFMA per wave per K-tile.
// P1: 12 reads + 16 MFMA; P2: 8 reads + 32 MFMA over staging. Counted vmcnt(4).
__global__ __launch_bounds__(512, 2)
void gemm_qkv(const unsigned short* __restrict__ A, const unsigned short* __restrict__ B,
              unsigned short* __restrict__ C, int M, int N, int K) {
  __shared__ __align__(16) unsigned short lds[2][448 * 64];  // A rows 0..255, B rows 256..447
  const int t = threadIdx.x, lane = t & 63, w = t >> 6;
  const int wm = w >> 1, wn = w & 1;              // 4M x 2N
  const int r16 = lane & 15, kg = lane >> 4;
  const int bm = blockIdx.x & 7, bn = blockIdx.x >> 3;  // XCD = bid%8 = bm: A panel L2-resident
  const int NT = K >> 6;
  const int sr = lane >> 3, sch = lane & 7;
  const unsigned short* Ag = A + (size_t)(bm * 256) * K;
  const unsigned short* Bg = B + (size_t)(bn * 192) * K;

  auto stA = [&](int kt, int j, int b) {
    int rl = j * 64 + w * 8 + sr, sc = sch ^ (rl & 7);
    GLOAD_LDS16(Ag + (size_t)rl * K + kt * 64 + sc * 8, &lds[b][(j * 64 + w * 8) * 64]);
  };
  auto stB = [&](int kt, int j, int b) {
    int rl = j * 64 + w * 8 + sr, sc = sch ^ (rl & 7);
    GLOAD_LDS16(Bg + (size_t)rl * K + kt * 64 + sc * 8, &lds[b][(256 + j * 64 + w * 8) * 64]);
  };
  auto lda = [&](int b, int m, int kk) -> short8 {
    int row = wm * 64 + m * 16 + r16, ch = (kk * 4 + kg) ^ (row & 7);
    return *(const short8*)__builtin_assume_aligned(&lds[b][row * 64 + ch * 8], 16);
  };
  auto ldb = [&](int b, int n, int kk) -> short8 {
    int row = wn * 96 + n * 16 + r16, ch = (kk * 4 + kg) ^ (row & 7);
    return *(const short8*)__builtin_assume_aligned(&lds[b][(256 + row) * 64 + ch * 8], 16);
  };

  f32x4 acc[4][6] = {};
  short8 af[4][2], bb[6][2];

  // prologue: tile0 full (A 4 + B 3); tile1's A (4). B(1) spills into t0's P1.
#pragma unroll
  for (int j = 0; j < 4; ++j) stA(0, j, 0);
#pragma unroll
  for (int j = 0; j < 3; ++j) stB(0, j, 0);
#pragma unroll
  for (int j = 0; j < 4; ++j) stA(1, j, 1);
  asm volatile("s_waitcnt vmcnt(4)" ::: "memory");
  __builtin_amdgcn_sched_barrier(0);
  __builtin_amdgcn_s_barrier();

  for (int kt = 0; kt < NT; ++kt) {
    const int b = kt & 1;
    const bool pf1 = kt + 1 < NT, pf2 = kt + 2 < NT;

    // ---- P1: spill-stage B0-2(t+1) into b^1 (all b^1 B-reads done @t-1 end);
    //          read a(8)+b01(4); MFMA m0-3 x n0-1 (16) ----
    if (pf1) { stB(kt + 1, 0, b ^ 1); stB(kt + 1, 1, b ^ 1); stB(kt + 1, 2, b ^ 1); }
#pragma unroll
    for (int m = 0; m < 4; ++m) { af[m][0] = lda(b, m, 0); af[m][1] = lda(b, m, 1); }
#pragma unroll
    for (int n = 0; n < 2; ++n) { bb[n][0] = ldb(b, n, 0); bb[n][1] = ldb(b, n, 1); }
    __builtin_amdgcn_s_barrier();
    LGKM0();
    __builtin_amdgcn_s_setprio(1);
#pragma unroll
    for (int m = 0; m < 4; ++m)
#pragma unroll
      for (int n = 0; n < 2; ++n)
#pragma unroll
        for (int kk = 0; kk < 2; ++kk) acc[m][n] = MFMA16(af[m][kk], bb[n][kk], acc[m][n]);
    __builtin_amdgcn_s_setprio(0);
    __builtin_amdgcn_s_barrier();

    // ---- P2: stage A0-3(t+2) into b (A-reads done @P1-end barrier);
    //          read b2-5(8); MFMA m0-3 x n2-5 (32) ----
    if (pf2) { stA(kt + 2, 0, b); stA(kt + 2, 1, b); stA(kt + 2, 2, b); stA(kt + 2, 3, b); }
#pragma unroll
    for (int n = 2; n < 6; ++n) { bb[n][0] = ldb(b, n, 0); bb[n][1] = ldb(b, n, 1); }
    __builtin_amdgcn_s_barrier();
    LGKM0();
    __builtin_amdgcn_s_setprio(1);
#pragma unroll
    for (int m = 0; m < 4; ++m)
#pragma unroll
      for (int n = 2; n < 6; ++n)
#pragma unroll
        for (int kk = 0; kk < 2; ++kk) acc[m][n] = MFMA16(af[m][kk], bb[n][kk], acc[m][n]);
    __builtin_amdgcn_s_setprio(0);
    if (pf1) {  // drain through B(t+1)'s 3; keep A(t+2)'s 4 in flight
      if (pf2) asm volatile("s_waitcnt vmcnt(4)" ::: "memory");
      else     asm volatile("s_waitcnt vmcnt(0)" ::: "memory");
      __builtin_amdgcn_sched_barrier(0);
      __builtin_amdgcn_s_barrier();
    }
  }

#pragma unroll
  for (int m = 0; m < 4; ++m)
#pragma unroll
    for (int n = 0; n < 6; ++n)
#pragma unroll
      for (int j = 0; j < 4; ++j) {
        int row = bm * 256 + wm * 64 + m * 16 + kg * 4 + j;
        int col = bn * 192 + wn * 96 + n * 16 + r16;
        C[(size_t)row * N + col] = f2bf(acc[m][n][j]);
      }
}

// ======== GEMM2: BM=128 x BN=256, grid 16x16=256, 4 phases/K-tile, f32 out ========
__global__ __launch_bounds__(512, 1)
void gemm_proj(const unsigned short* __restrict__ A, const unsigned short* __restrict__ B,
               float* __restrict__ C, int M, int N, int K) {
  __shared__ __align__(16) unsigned short lds[2][384 * 64];  // A rows 0-127, B rows 128-383
  const int t = threadIdx.x, lane = t & 63, w = t >> 6;
  const int wm = w >> 2, wn = w & 3;
  const int r16 = lane & 15, kg = lane >> 4;
  const int bm = blockIdx.x & 15, bn = blockIdx.x >> 4;
  const int NT = K >> 6;
  const int sr = lane >> 3, sch = lane & 7;
  const unsigned short* Ag = A + (size_t)(bm * 128) * K;
  const unsigned short* Bg = B + (size_t)(bn * 256) * K;

  auto stA = [&](int kt, int j, int b) {
    int rl = j * 64 + w * 8 + sr, sc = sch ^ (rl & 7);
    GLOAD_LDS16(Ag + (size_t)rl * K + kt * 64 + sc * 8, &lds[b][(j * 64 + w * 8) * 64]);
  };
  auto stB = [&](int kt, int j, int b) {
    int rl = j * 64 + w * 8 + sr, sc = sch ^ (rl & 7);
    GLOAD_LDS16(Bg + (size_t)rl * K + kt * 64 + sc * 8, &lds[b][(128 + j * 64 + w * 8) * 64]);
  };
  auto lda = [&](int b, int m, int kk) -> short8 {
    int row = wm * 64 + m * 16 + r16, ch = (kk * 4 + kg) ^ (row & 7);
    return *(const short8*)__builtin_assume_aligned(&lds[b][row * 64 + ch * 8], 16);
  };
  auto ldb = [&](int b, int n, int kk) -> short8 {
    int row = wn * 64 + n * 16 + r16, ch = (kk * 4 + kg) ^ (row & 7);
    return *(const short8*)__builtin_assume_aligned(&lds[b][(128 + row) * 64 + ch * 8], 16);
  };

  f32x4 acc[4][4] = {};
  short8 af[4][2], bb[4][2];

  // prologue: tiles 0 and 1 fully staged (6 issues each); keep tile1's 6 in flight
#pragma unroll
  for (int j = 0; j < 2; ++j) stA(0, j, 0);
#pragma unroll
  for (int j = 0; j < 4; ++j) stB(0, j, 0);
#pragma unroll
  for (int j = 0; j < 2; ++j) stA(1, j, 1);
#pragma unroll
  for (int j = 0; j < 4; ++j) stB(1, j, 1);
  asm volatile("s_waitcnt vmcnt(6)" ::: "memory");
  __builtin_amdgcn_sched_barrier(0);
  __builtin_amdgcn_s_barrier();

  for (int kt = 0; kt < NT; ++kt) {
    const int b = kt & 1;
    const bool pf1 = kt + 1 < NT, pf2 = kt + 2 < NT;

    // ---- P1: read a01(4)+b01(4); MFMA m0-1 x n0-1 ----
#pragma unroll
    for (int m = 0; m < 2; ++m) { af[m][0] = lda(b, m, 0); af[m][1] = lda(b, m, 1); }
#pragma unroll
    for (int n = 0; n < 2; ++n) { bb[n][0] = ldb(b, n, 0); bb[n][1] = ldb(b, n, 1); }
    __builtin_amdgcn_s_barrier();
    LGKM0();
    __builtin_amdgcn_s_setprio(1);
#pragma unroll
    for (int m = 0; m < 2; ++m)
#pragma unroll
      for (int n = 0; n < 2; ++n)
#pragma unroll
        for (int kk = 0; kk < 2; ++kk) acc[m][n] = MFMA16(af[m][kk], bb[n][kk], acc[m][n]);
    __builtin_amdgcn_s_setprio(0);
    __builtin_amdgcn_s_barrier();

    // ---- P2: read b23(4); MFMA m0-1 x n2-3 ----
#pragma unroll
    for (int n = 2; n < 4; ++n) { bb[n][0] = ldb(b, n, 0); bb[n][1] = ldb(b, n, 1); }
    __builtin_amdgcn_s_barrier();
    LGKM0();
    __builtin_amdgcn_s_setprio(1);
#pragma unroll
    for (int m = 0; m < 2; ++m)
#pragma unroll
      for (int n = 2; n < 4; ++n)
#pragma unroll
        for (int kk = 0; kk < 2; ++kk) acc[m][n] = MFMA16(af[m][kk], bb[n][kk], acc[m][n]);
    __builtin_amdgcn_s_setprio(0);
    __builtin_amdgcn_s_barrier();

    // ---- P3: read a23(4); stage B0-3(t+2) (freed @P2-end); MFMA m2-3 x n2-3 ----
#pragma unroll
    for (int m = 2; m < 4; ++m) { af[m][0] = lda(b, m, 0); af[m][1] = lda(b, m, 1); }
    if (pf2) { stB(kt + 2, 0, b); stB(kt + 2, 1, b); stB(kt + 2, 2, b); stB(kt + 2, 3, b); }
    __builtin_amdgcn_s_barrier();
    LGKM0();
    __builtin_amdgcn_s_setprio(1);
#pragma unroll
    for (int m = 2; m < 4; ++m)
#pragma unroll
      for (int n = 2; n < 4; ++n)
#pragma unroll
        for (int kk = 0; kk < 2; ++kk) acc[m][n] = MFMA16(af[m][kk], bb[n][kk], acc[m][n]);
    __builtin_amdgcn_s_setprio(0);
    __builtin_amdgcn_s_barrier();

    // ---- P4: stage A0,A1(t+2) (freed @P3-end); MFMA m2-3 x n0-1 (regs only) ----
    if (pf2) { stA(kt + 2, 0, b); stA(kt + 2, 1, b); }
    __builtin_amdgcn_s_setprio(1);
#pragma unroll
    for (int m = 2; m < 4; ++m)
#pragma unroll
      for (int n = 0; n < 2; ++n)
#pragma unroll
        for (int kk = 0; kk < 2; ++kk) acc[m][n] = MFMA16(af[m][kk], bb[n][kk], acc[m][n]);
    __builtin_amdgcn_s_setprio(0);
    if (pf1) {
      if (pf2) asm volatile("s_waitcnt vmcnt(6)" ::: "memory");
      else     asm volatile("s_waitcnt vmcnt(0)" ::: "memory");
      __builtin_amdgcn_sched_barrier(0);
      __builtin_amdgcn_s_barrier();
    }
  }

#pragma unroll
  for (int m = 0; m < 4; ++m)
#pragma unroll
    for (int n = 0; n < 4; ++n)
#pragma unroll
      for (int j = 0; j < 4; ++j) {
        int row = bm * 128 + wm * 64 + m * 16 + kg * 4 + j;
        int col = bn * 256 + wn * 64 + n * 16 + r16;
        C[(size_t)row * N + col] = acc[m][n][j];
      }
}

// -------- Merged RoPE (Q with 1/sqrt(hs), K) + V transpose: one dispatch --------
__global__ void rope_tv(const unsigned short* __restrict__ qkv,
                        const float* __restrict__ cosb, const float* __restrict__ sinb,
                        unsigned short* __restrict__ Q, unsigned short* __restrict__ K,
                        unsigned short* __restrict__ Vt) {
  __shared__ __align__(16) unsigned short tile[64][136];
  const int bid = blockIdx.x;
  if (bid < 20480) {
    int pair = bid * 4 + (threadIdx.x >> 6);
    int l = threadIdx.x & 63;
    int t = pair / 40, slot = pair - t * 40;
    const unsigned short* src;
    unsigned short* dst;
    float scale;
    if (slot < 32) {
      int g = slot >> 2, j = slot & 3;
      src = qkv + (size_t)t * 6144 + g * 768 + j * 128;
      dst = Q + ((size_t)slot * 2048 + t) * 128;
      scale = 0.08838834764831845f;  // 1/sqrt(128)
    } else {
      int g = slot - 32;
      src = qkv + (size_t)t * 6144 + g * 768 + 512;
      dst = K + ((size_t)g * 2048 + t) * 128;
      scale = 1.0f;
    }
    float x1 = bf2f(src[l]), x2 = bf2f(src[64 + l]);
    float c1 = cosb[t * 128 + l], s1 = sinb[t * 128 + l];
    float c2 = cosb[t * 128 + 64 + l], s2 = sinb[t * 128 + 64 + l];
    dst[l]      = f2bf((x1 * c1 - x2 * s1) * scale);
    dst[64 + l] = f2bf((x2 * c2 + x1 * s2) * scale);
  } else {
    int b2 = bid - 20480;              // 0..255
    int g = b2 >> 5, t0 = (b2 & 31) * 64;
    int th = threadIdx.x;
    int r = th >> 2, c0 = (th & 3) * 32;
    const unsigned short* src = qkv + (size_t)(t0 + r) * 6144 + g * 768 + 640 + c0;
#pragma unroll
    for (int i = 0; i < 4; ++i)
      *(short8*)&tile[r][c0 + i * 8] = *(const short8*)(src + i * 8);
    __syncthreads();
    int d = th >> 1, tc = (th & 1) * 32;
    unsigned short* dst = Vt + (size_t)(g * 128 + d) * 2048 + t0 + tc;
#pragma unroll
    for (int j = 0; j < 32; ++j) dst[j] = tile[tc + j][d];
  }
}

// ---------------- Flash attention (R5-verbatim): swapped QK^T, in-reg softmax, ----
// ---------------- dbuf + 1 barrier/tile, paired q-tiles (33 KV tiles/block) ------
__global__ __launch_bounds__(256, 2)
void flash_attn(const unsigned short* __restrict__ Q, const unsigned short* __restrict__ K,
                const unsigned short* __restrict__ Vt, unsigned short* __restrict__ Y) {
  __shared__ __align__(16) unsigned short Ksm[2][64 * 128];   // [kv][d], XOR-swizzled
  __shared__ __align__(16) unsigned short Vsm[2][128 * 64];   // [d][kv], XOR-swizzled

  const int h = blockIdx.y, g = h >> 2;
  const int t = threadIdx.x, lane = t & 63, w = t >> 6;
  const int r16 = lane & 15, kg = lane >> 4;
  const bool odd = kg & 1;
  const bool hi = kg >> 1;
  const bool useswap = odd ^ hi;

  const unsigned short* Kg = K + (size_t)g * 2048 * 128;
  const unsigned short* Vg = Vt + (size_t)g * 128 * 2048;

  const int krl = lane >> 4, kc = lane & 15;
  const int vrl = lane >> 3, vc = lane & 7;

  auto stage = [&](int kvs, int b) {
#pragma unroll
    for (int i = 0; i < 4; ++i) {
      int row = w * 16 + i * 4 + krl;
      int sc = kc ^ (row & 7);
      GLOAD_LDS16(Kg + (size_t)(kvs + row) * 128 + sc * 8,
                  &Ksm[b][(w * 16 + i * 4) * 128]);
    }
#pragma unroll
    for (int i = 0; i < 4; ++i) {
      int d = w * 32 + i * 8 + vrl;
      int sc = vc ^ (d & 7);
      GLOAD_LDS16(Vg + (size_t)d * 2048 + kvs + sc * 8,
                  &Vsm[b][(w * 32 + i * 8) * 64]);
    }
  };

  auto process = [&](int q0) {
    short8 qf[4];
    const unsigned short* qrow = Q + ((size_t)h * 2048 + q0 + w * 16 + r16) * 128;
#pragma unroll
    for (int kk = 0; kk < 4; ++kk) qf[kk] = *(const short8*)(qrow + kk * 32 + kg * 8);

    f32x4 o[8] = {};
    float mrow = -1e30f, lrow = 0.f;
    const int qg = q0 + w * 16 + r16;
    const int nt = q0 / 64 + 1;

    __syncthreads();
    stage(0, 0);

    for (int kt = 0; kt < nt; ++kt) {
      const int b = kt & 1;
      const int kv0 = kt * 64;
      __syncthreads();
      if (kt + 1 < nt) stage((kt + 1) * 64, b ^ 1);

      f32x4 s[4] = {};
      __builtin_amdgcn_s_setprio(1);
#pragma unroll
      for (int n = 0; n < 4; ++n) {
        int kr = n * 16 + r16;
#pragma unroll
        for (int kk = 0; kk < 4; ++kk) {
          short8 kf = *(const short8*)__builtin_assume_aligned(
              &Ksm[b][kr * 128 + ((kk * 32 + kg * 8) ^ ((kr & 7) << 3))], 16);
          s[n] = __builtin_amdgcn_mfma_f32_16x16x32_bf16(kf, qf[kk], s[n], 0, 0, 0);
        }
      }
      __builtin_amdgcn_s_setprio(0);

      if (kv0 + 63 > q0 + w * 16) {
#pragma unroll
        for (int n = 0; n < 4; ++n)
#pragma unroll
          for (int j = 0; j < 4; ++j)
            if (kv0 + n * 16 + kg * 4 + j > qg) s[n][j] = -1e30f;
      }

      float rmax = -1e30f;
#pragma unroll
      for (int n = 0; n < 4; ++n)
#pragma unroll
        for (int j = 0; j < 4; ++j) rmax = fmaxf(rmax, s[n][j]);
      rmax = fmaxf(rmax, __shfl_xor(rmax, 16));
      rmax = fmaxf(rmax, __shfl_xor(rmax, 32));

      if (__builtin_amdgcn_ballot_w64(rmax > mrow)) {
        float mnew = fmaxf(mrow, rmax);
        float fac = __expf(mrow - mnew);
        mrow = mnew;
        lrow *= fac;
        float fj[4];
#pragma unroll
        for (int j = 0; j < 4; ++j) fj[j] = __shfl(fac, kg * 4 + j);
#pragma unroll
        for (int f = 0; f < 8; ++f)
#pragma unroll
          for (int j = 0; j < 4; ++j) o[f][j] *= fj[j];
      }

      float p[4][4];
      float rs = 0.f;
#pragma unroll
      for (int n = 0; n < 4; ++n)
#pragma unroll
        for (int j = 0; j < 4; ++j) {
          p[n][j] = __expf(s[n][j] - mrow);
          rs += p[n][j];
        }
      rs += __shfl_xor(rs, 16);
      rs += __shfl_xor(rs, 32);
      lrow += rs;

      unsigned bpk[4][2], xpk[4][2];
#pragma unroll
      for (int n = 0; n < 4; ++n)
#pragma unroll
        for (int i = 0; i < 2; ++i)
          bpk[n][i] = (unsigned)f2bf(p[n][2 * i]) | ((unsigned)f2bf(p[n][2 * i + 1]) << 16);
#pragma unroll
      for (int n = 0; n < 4; ++n)
#pragma unroll
        for (int i = 0; i < 2; ++i) xpk[n][i] = __shfl_xor(bpk[n][i], 16);

      unsigned pl[4][2], ph[4][2];
#pragma unroll
      for (int n = 0; n < 4; ++n)
#pragma unroll
        for (int i = 0; i < 2; ++i) {
          pl[n][i] = odd ? xpk[n][i] : bpk[n][i];
          ph[n][i] = odd ? bpk[n][i] : xpk[n][i];
        }

      short8 pa[2];
#pragma unroll
      for (int kk = 0; kk < 2; ++kk) {
        unsigned kp0 = hi ? pl[2 * kk + 1][0] : pl[2 * kk][0];
        unsigned kp1 = hi ? pl[2 * kk + 1][1] : pl[2 * kk][1];
        unsigned kp2 = hi ? ph[2 * kk + 1][0] : ph[2 * kk][0];
        unsigned kp3 = hi ? ph[2 * kk + 1][1] : ph[2 * kk][1];
        unsigned sd0 = hi ? pl[2 * kk][0] : pl[2 * kk + 1][0];
        unsigned sd1 = hi ? pl[2 * kk][1] : pl[2 * kk + 1][1];
        unsigned sd2 = hi ? ph[2 * kk][0] : ph[2 * kk + 1][0];
        unsigned sd3 = hi ? ph[2 * kk][1] : ph[2 * kk + 1][1];
        unsigned g0 = __shfl_xor(sd0, 32), g1 = __shfl_xor(sd1, 32);
        unsigned g2 = __shfl_xor(sd2, 32), g3 = __shfl_xor(sd3, 32);
        union { unsigned u[4]; short8 v; } pu;
        pu.u[0] = useswap ? g0 : kp0;
        pu.u[1] = useswap ? g1 : kp1;
        pu.u[2] = useswap ? g2 : kp2;
        pu.u[3] = useswap ? g3 : kp3;
        pa[kk] = pu.v;
      }

      __builtin_amdgcn_s_setprio(1);
#pragma unroll
      for (int kk = 0; kk < 2; ++kk) {
#pragma unroll
        for (int f = 0; f < 8; ++f) {
          int d = f * 16 + r16;
          short8 vf = *(const short8*)__builtin_assume_aligned(
              &Vsm[b][d * 64 + ((kk * 32 + kg * 8) ^ ((d & 7) << 3))], 16);
          o[f] = __builtin_amdgcn_mfma_f32_16x16x32_bf16(pa[kk], vf, o[f], 0, 0, 0);
        }
      }
      __builtin_amdgcn_s_setprio(0);
    }

    float inv = 1.f / lrow;
    float invj[4];
#pragma unroll
    for (int j = 0; j < 4; ++j) invj[j] = __shfl(inv, kg * 4 + j);
#pragma unroll
    for (int j = 0; j < 4; ++j) {
      int row = q0 + w * 16 + kg * 4 + j;
      unsigned short* yr = Y + (size_t)row * 4096 + h * 128;
#pragma unroll
      for (int f = 0; f < 8; ++f) yr[f * 16 + r16] = f2bf(o[f][j] * invj[j]);
    }
  };

  const int pr = blockIdx.x;      // 0..15
  process(pr * 64);               // light tile
  process((31 - pr) * 64);        // heavy tile: total 33 KV-tiles per block
}

extern "C" void kernel_launch(void* const* d_in, const int* in_sizes, int n_in,
                              void* d_out, int out_size, void* d_ws, size_t ws_size,
                              hipStream_t stream) {
  const float* x      = (const float*)d_in[0];
  const float* cosb   = (const float*)d_in[1];
  const float* sinb   = (const float*)d_in[2];
  const float* w_attn = (const float*)d_in[3];
  const float* w_proj = (const float*)d_in[4];
  float* out = (float*)d_out;

  char* ws = (char*)d_ws;
  const size_t MB = 1024 * 1024;
  unsigned short* Xb  = (unsigned short*)(ws);
  unsigned short* Wa  = (unsigned short*)(ws + 16 * MB);
  unsigned short* Wp  = (unsigned short*)(ws + 112 * MB);
  unsigned short* Qb  = (unsigned short*)(ws + 32 * MB);  // after gemm1
  unsigned short* Kb  = (unsigned short*)(ws + 48 * MB);  // after gemm1
  unsigned short* Vt  = (unsigned short*)(ws + 52 * MB);  // after gemm1
  unsigned short* qkv = (unsigned short*)(ws + 64 * MB);
  unsigned short* Yb  = (unsigned short*)(ws + 88 * MB);

  cvt3<<<2048, 256, 0, stream>>>(x, w_attn, w_proj, Xb, Wa, Wp);
  gemm_qkv<<<256, 512, 0, stream>>>(Xb, Wa, qkv, 2048, 6144, 4096);
  rope_tv<<<20736, 256, 0, stream>>>(qkv, cosb, sinb, Qb, Kb, Vt);
  flash_attn<<<dim3(16, 32), 256, 0, stream>>>(Qb, Kb, Vt, Yb);
  gemm_proj<<<256, 512, 0, stream>>>(Yb, Wp, out, 2048, 4096, 4096);
}